// Round 10
// baseline (229.539 us; speedup 1.0000x reference)
//
#include <hip/hip_runtime.h>
#include <cstdint>

#define HW 3136
#define WID 56
#define NBLK 1792   // 32 frame-pairs * 56 rows

__device__ __forceinline__ int clampi(int v, int lo, int hi) {
    return v < lo ? lo : (v > hi ? hi : v);
}

__device__ __forceinline__ float bperm(int a4, float v) {
    return __int_as_float(__builtin_amdgcn_ds_bpermute(a4, __float_as_int(v)));
}

__device__ __forceinline__ void fma4(float4& a, const float4& u, const float4& w) {
    a.x += u.x * w.x; a.y += u.y * w.y; a.z += u.z * w.z; a.w += u.w * w.w;
}

// Quad-pixel restructure: thread = 4 adjacent pixels (float4) of one channel
// slice. Lane l: qd = l&15 (active <14 -> 14 quads = 56 px), s16 = wave*4 +
// (l>>4) in 0..15. All global taps are b128; dj shifts are register-element
// selects; only the 2 quad-edge words use bperm (+select for image edge).
// Phase 1: corr (2 ch/slice per 32-ch group) -> CP float4 reduce over 16
// slices (two ij-halves to halve CP) -> CR[72][56] in LDS.
// Hoist: 18 float4 weights/thread (both frames, gl = s16&7).
// Phase 3: 16 iters x 1 ch (ch = k*16+s16), 6 b128 loads + 12 bperm + 72 FMA.
// LDS 34 KB -> 4 blocks/CU; VGPR target <=128.
__global__ __launch_bounds__(256, 2) void tf_fused(
    const float* __restrict__ x, const float* __restrict__ wconv,
    const float* __restrict__ bconv, float* __restrict__ out)
{
    __shared__ float4 CP[16 * 5 * 14];   // 17920 B
    __shared__ float  CR[72 * 56];       // 16128 B

    const int d = blockIdx.x;
    const int logical = (d & 7) * 224 + (d >> 3);   // XCD-contiguous rows
    const int n  = logical / 56;
    const int r0 = logical % 56;
    const int t = threadIdx.x;
    const int wv = t >> 6;
    const int l = t & 63;
    const int qd0 = l & 15;
    const int s16 = wv * 4 + (l >> 4);
    const bool act = qd0 < 14;
    const int qd = act ? qd0 : 13;
    const int gl = s16 & 7;

    const float* xe = x + (size_t)(2 * n) * 256 * HW;
    const float* xo = xe + (size_t)256 * HW;

    // quad-edge bperm lane addresses; image-edge clamp handled by le/re selects
    const int am = ((qd0 == 0) ? l : (l - 1)) * 4;
    const int ap = ((qd0 >= 13) ? l : (l + 1)) * 4;
    const bool le = (qd0 == 0);    // px 0: left tap = own .x
    const bool re = (qd0 >= 13);   // px 55: right tap = own .w

    int rb[3];   // row bases (edge-clamped), fully unrolled use only
    #pragma unroll
    for (int di = 0; di < 3; ++di) rb[di] = clampi(r0 + di - 1, 0, 55) * WID + qd * 4;
    const int rc = r0 * WID + qd * 4;

    // build shifted tap triple from own float4 (2 bperm + 2 selects)
#define MKTAPS(v, Tm, Tp)                                   \
    {                                                       \
        const float lwp = bperm(am, (v).w);                 \
        const float rwp = bperm(ap, (v).x);                 \
        const float lw = le ? (v).x : lwp;                  \
        const float rw = re ? (v).w : rwp;                  \
        Tm = make_float4(lw, (v).x, (v).y, (v).z);          \
        Tp = make_float4((v).y, (v).z, (v).w, rw);          \
    }

    // ================= phase 1: corr -> CR =================
    for (int g = 0; g < 8; ++g) {
        const int ch0 = g * 32 + 2 * s16;
        const float* pe = xe + (size_t)ch0 * HW;
        const float* po = xo + (size_t)ch0 * HW;
        const float4 E0 = *(const float4*)(pe + rc);
        const float4 E1 = *(const float4*)(pe + HW + rc);

        float4 crg[9];
        #pragma unroll
        for (int i = 0; i < 9; ++i) crg[i] = make_float4(0.f, 0.f, 0.f, 0.f);

        #pragma unroll
        for (int di = 0; di < 3; ++di) {
            const float4 O0 = *(const float4*)(po + rb[di]);
            const float4 O1 = *(const float4*)(po + HW + rb[di]);
            float4 T0m, T0p, T1m, T1p;
            MKTAPS(O0, T0m, T0p)
            MKTAPS(O1, T1m, T1p)
            fma4(crg[di * 3 + 0], E0, T0m); fma4(crg[di * 3 + 0], E1, T1m);
            fma4(crg[di * 3 + 1], E0, O0);  fma4(crg[di * 3 + 1], E1, O1);
            fma4(crg[di * 3 + 2], E0, T0p); fma4(crg[di * 3 + 2], E1, T1p);
        }

        // ---- reduce over 16 slices, ij-half 1 (0..4) ----
        if (act) {
            #pragma unroll
            for (int ij = 0; ij < 5; ++ij) CP[(s16 * 5 + ij) * 14 + qd] = crg[ij];
        }
        __syncthreads();
        if (t < 70) {
            const int ij = t / 14, qu = t % 14;
            float4 s = CP[ij * 14 + qu];
            #pragma unroll
            for (int sl = 1; sl < 16; ++sl) {
                const float4 v = CP[(sl * 5 + ij) * 14 + qu];
                s.x += v.x; s.y += v.y; s.z += v.z; s.w += v.w;
            }
            *(float4*)(CR + (ij * 8 + g) * 56 + qu * 4) = s;
        }
        __syncthreads();
        // ---- ij-half 2 (5..8) ----
        if (act) {
            #pragma unroll
            for (int ij = 5; ij < 9; ++ij) CP[(s16 * 5 + ij - 5) * 14 + qd] = crg[ij];
        }
        __syncthreads();
        if (t < 56) {
            const int ij = 5 + t / 14, qu = t % 14;
            float4 s = CP[(ij - 5) * 14 + qu];
            #pragma unroll
            for (int sl = 1; sl < 16; ++sl) {
                const float4 v = CP[(sl * 5 + ij - 5) * 14 + qu];
                s.x += v.x; s.y += v.y; s.z += v.z; s.w += v.w;
            }
            *(float4*)(CR + (ij * 8 + g) * 56 + qu * 4) = s;
        }
        __syncthreads();
    }

    // ---- hoist: 18 float4 weights for this thread's gl at its 4 px ----
    float4 We[9], Wo[9];
    #pragma unroll
    for (int ij = 0; ij < 9; ++ij) {
        const int fe = ij * 16 + 2 * gl;     // even-frame weight; fe+1 = odd
        const int a = fe / 18;               // (fe+1)/18 == a since fe even
        const float be = bconv[fe], bo = bconv[fe + 1];
        float4 we = make_float4(be, be, be, be);
        float4 wo = make_float4(bo, bo, bo, bo);
        #pragma unroll
        for (int b = 0; b < 9; ++b) {
            const float4 c4 = *(const float4*)(CR + (a * 9 + b) * 56 + qd * 4);
            const float wce = wconv[fe * 9 + b];
            const float wco = wconv[fe * 9 + 9 + b];
            we.x += c4.x * wce; we.y += c4.y * wce; we.z += c4.z * wce; we.w += c4.w * wce;
            wo.x += c4.x * wco; wo.y += c4.y * wco; wo.z += c4.z * wco; wo.w += c4.w * wco;
        }
        We[ij] = we; Wo[ij] = wo;
    }

    // ================= phase 3: barrier-free weighted gather =================
    float* ob = out + (size_t)n * 256 * HW + r0 * WID + qd * 4;

    for (int k = 0; k < 16; ++k) {
        const int ch = k * 16 + s16;
        const float* pe = xe + (size_t)ch * HW;
        const float* po = xo + (size_t)ch * HW;

        float4 acc = make_float4(0.f, 0.f, 0.f, 0.f);
        #pragma unroll
        for (int di = 0; di < 3; ++di) {
            const float4 E = *(const float4*)(pe + rb[di]);
            const float4 O = *(const float4*)(po + rb[di]);
            float4 TEm, TEp, TOm, TOp;
            MKTAPS(E, TEm, TEp)
            MKTAPS(O, TOm, TOp)
            fma4(acc, TEm, We[di * 3 + 0]); fma4(acc, TOm, Wo[di * 3 + 0]);
            fma4(acc, E,   We[di * 3 + 1]); fma4(acc, O,   Wo[di * 3 + 1]);
            fma4(acc, TEp, We[di * 3 + 2]); fma4(acc, TOp, Wo[di * 3 + 2]);
        }
        if (act) *(float4*)(ob + (size_t)ch * HW) = acc;
    }
#undef MKTAPS
}

// partial BN stats: block bid -> channel bid>>3, frame-pair slice bid&7 (4 pairs)
__global__ void tf_stats_part(const float* __restrict__ out,
                              float* __restrict__ ps, float* __restrict__ pq)
{
    const int ch = blockIdx.x >> 3;
    const int sl = blockIdx.x & 7;
    const int t = threadIdx.x;

    float s = 0.f, q = 0.f;
    #pragma unroll
    for (int k = 0; k < 4; ++k) {
        const float4* p = (const float4*)(out + ((size_t)(4 * sl + k) * 256 + ch) * HW);
        for (int i = t; i < 784; i += 256) {
            const float4 v = p[i];
            s += v.x + v.y + v.z + v.w;
            q += v.x * v.x + v.y * v.y + v.z * v.z + v.w * v.w;
        }
    }
    #pragma unroll
    for (int o = 32; o >= 1; o >>= 1) {
        s += __shfl_xor(s, o);
        q += __shfl_xor(q, o);
    }
    __shared__ float rs[4], rq[4];
    if ((t & 63) == 0) { rs[t >> 6] = s; rq[t >> 6] = q; }
    __syncthreads();
    if (t == 0) {
        ps[blockIdx.x] = rs[0] + rs[1] + rs[2] + rs[3];
        pq[blockIdx.x] = rq[0] + rq[1] + rq[2] + rq[3];
    }
}

__global__ void tf_stats_fin(const float* __restrict__ ps, const float* __restrict__ pq,
                             const float* __restrict__ gamma, const float* __restrict__ beta,
                             float* __restrict__ AB)
{
    const int ch = threadIdx.x;   // 256 threads, 1 block
    float s = 0.f, q = 0.f;
    #pragma unroll
    for (int sl = 0; sl < 8; ++sl) {
        s += ps[ch * 8 + sl];
        q += pq[ch * 8 + sl];
    }
    const float inv = 1.f / 100352.f;   // nt2*h*w
    const float mean = s * inv;
    const float var = q * inv - mean * mean;
    const float rstd = rsqrtf(var + 1e-5f);
    const float A = gamma[ch] * rstd;
    AB[ch] = A;
    AB[256 + ch] = beta[ch] - mean * A;
}

__global__ void tf_norm(float* __restrict__ out, const float* __restrict__ AB)
{
    const unsigned total4 = 32u * 256u * 784u;  // 6,422,528 float4
    unsigned i = blockIdx.x * 256u + threadIdx.x;
    const unsigned stride = gridDim.x * 256u;
    float4* o4 = (float4*)out;
    for (; i < total4; i += stride) {
        const unsigned ch = (i / 784u) & 255u;
        const float A = AB[ch], B = AB[256 + ch];
        float4 v = o4[i];
        v.x = v.x * A + B;
        v.y = v.y * A + B;
        v.z = v.z * A + B;
        v.w = v.w * A + B;
        o4[i] = v;
    }
}

extern "C" void kernel_launch(void* const* d_in, const int* in_sizes, int n_in,
                              void* d_out, int out_size, void* d_ws, size_t ws_size,
                              hipStream_t stream) {
    const float* x     = (const float*)d_in[0];
    const float* wconv = (const float*)d_in[1];
    const float* bconv = (const float*)d_in[2];
    const float* gamma = (const float*)d_in[3];
    const float* beta  = (const float*)d_in[4];
    float* out = (float*)d_out;

    float* ps = (float*)d_ws;        // [2048]
    float* pq = ps + 2048;           // [2048]
    float* AB = pq + 2048;           // [512]

    tf_fused<<<NBLK, 256, 0, stream>>>(x, wconv, bconv, out);
    tf_stats_part<<<2048, 256, 0, stream>>>(out, ps, pq);
    tf_stats_fin<<<1, 256, 0, stream>>>(ps, pq, gamma, beta, AB);
    tf_norm<<<2048, 256, 0, stream>>>(out, AB);
}

// Round 11
// 191.197 us; speedup vs baseline: 1.2005x; 1.2005x over previous
//
#include <hip/hip_runtime.h>
#include <cstdint>

#define HW 3136
#define WID 56
#define NBLK 1792   // 32 frame-pairs * 56 rows

__device__ __forceinline__ int clampi(int v, int lo, int hi) {
    return v < lo ? lo : (v > hi ? hi : v);
}

__device__ __forceinline__ float bperm(int a4, float v) {
    return __int_as_float(__builtin_amdgcn_ds_bpermute(a4, __float_as_int(v)));
}

__device__ __forceinline__ void fma2(float2& a, const float2& u, const float2& w) {
    a.x += u.x * w.x; a.y += u.y * w.y;
}

// float2 restructure with R9's residency preserved.
// Block = 1 output row (56 px) of one frame-pair; 256 thr = 4 waves.
// Lane: sub = l>>5 (2 channel-slices/wave), s8 = wv*2+sub in 0..7, qd = l&31
// (28 active = 56 px as float2 pairs). All taps are b64 loads; the +-1 column
// shifts are register selects + 2 bperms per vector (quad-edge only).
// Phase 1: per g (32 ch), slice handles 4 ch -> crg[9] float2; shfl_xor(32)
// folds the wave's 2 sub-slices; waves 0-2 publish CP, wave 3 adds own regs
// and writes CR[72][56]. 2 barriers/g, 16 total.
// LDS = CR 16128 + CP 6048 = 22176 B -> 7 blocks/CU (whole grid resident,
// the R9 property that round 10 lost). Phase 3 barrier-free: 32 ch-iters,
// 6 b64 loads + 12 bperm + 36 FMA, weights in 18 float2 regs.
// VGPR target <= 72 (7 waves/SIMD); (256,2) = the only non-spilling config.
__global__ __launch_bounds__(256, 2) void tf_fused(
    const float* __restrict__ x, const float* __restrict__ wconv,
    const float* __restrict__ bconv, float* __restrict__ out)
{
    __shared__ float2 CP[3 * 9 * 28];   // 6048 B
    __shared__ float  CR[72 * 56];      // 16128 B

    const int d = blockIdx.x;
    const int logical = (d & 7) * 224 + (d >> 3);   // XCD-contiguous rows
    const int n  = logical / 56;
    const int r0 = logical % 56;
    const int t = threadIdx.x;
    const int wv = t >> 6;
    const int l = t & 63;
    const int sub = l >> 5;             // 0..1
    const int s8 = wv * 2 + sub;        // channel slice 0..7
    const int qd0 = l & 31;
    const bool act = qd0 < 28;
    const int qd = act ? qd0 : 27;

    const float* xe = x + (size_t)(2 * n) * 256 * HW;
    const float* xo = xe + (size_t)256 * HW;

    // quad-edge bperm addresses (neighbor lane), image-edge via le/re selects
    const int am = ((qd0 == 0) ? l : (l - 1)) * 4;
    const int ap = ((qd0 >= 27) ? l : (l + 1)) * 4;
    const bool le = (qd0 == 0);    // px 0: left tap = own .x
    const bool re = (qd0 >= 27);   // px 55: right tap = own .y

    int rb[3];   // row bases (edge-clamped); fully-unrolled use only
    #pragma unroll
    for (int di = 0; di < 3; ++di) rb[di] = clampi(r0 + di - 1, 0, 55) * WID + qd * 2;
    const int rc = r0 * WID + qd * 2;

    // shifted tap pair from own float2: 2 bperm + 2 selects
#define MKTAPS2(v, Tm, Tp)                                  \
    {                                                       \
        const float lwp = bperm(am, (v).y);                 \
        const float rwp = bperm(ap, (v).x);                 \
        Tm = make_float2(le ? (v).x : lwp, (v).x);          \
        Tp = make_float2((v).y, re ? (v).y : rwp);          \
    }

    // ================= phase 1: corr -> CR =================
    for (int g = 0; g < 8; ++g) {
        const int ch0 = g * 32 + 4 * s8;
        const float* pe = xe + (size_t)ch0 * HW;
        const float* po = xo + (size_t)ch0 * HW;

        float2 crg[9];
        #pragma unroll
        for (int i = 0; i < 9; ++i) crg[i] = make_float2(0.f, 0.f);

        #pragma unroll
        for (int c = 0; c < 4; ++c) {
            const float2 E = *(const float2*)(pe + (size_t)c * HW + rc);
            #pragma unroll
            for (int di = 0; di < 3; ++di) {
                const float2 O = *(const float2*)(po + (size_t)c * HW + rb[di]);
                float2 Tm, Tp;
                MKTAPS2(O, Tm, Tp)
                fma2(crg[di * 3 + 0], E, Tm);
                fma2(crg[di * 3 + 1], E, O);
                fma2(crg[di * 3 + 2], E, Tp);
            }
        }

        // fold the wave's two sub-slices (lanes l and l^32 share qd)
        #pragma unroll
        for (int ij = 0; ij < 9; ++ij) {
            crg[ij].x += __shfl_xor(crg[ij].x, 32);
            crg[ij].y += __shfl_xor(crg[ij].y, 32);
        }

        if (wv < 3 && sub == 0 && act) {
            #pragma unroll
            for (int ij = 0; ij < 9; ++ij)
                CP[(wv * 9 + ij) * 28 + qd] = crg[ij];
        }
        __syncthreads();
        // wave 3 = sole reducer: own regs + 3 published slices -> CR
        if (wv == 3 && sub == 0 && act) {
            #pragma unroll
            for (int ij = 0; ij < 9; ++ij) {
                const float2 v0 = CP[(0 * 9 + ij) * 28 + qd];
                const float2 v1 = CP[(1 * 9 + ij) * 28 + qd];
                const float2 v2 = CP[(2 * 9 + ij) * 28 + qd];
                float2 v = crg[ij];
                v.x += v0.x + v1.x + v2.x;
                v.y += v0.y + v1.y + v2.y;
                *(float2*)(CR + (ij * 8 + g) * 56 + qd * 2) = v;
            }
        }
        __syncthreads();   // CR written; CP free for next g
    }

    // ---- hoist: 18 float2 weights (this thread's gl = s8, at its 2 px) ----
    float2 We[9], Wo[9];
    #pragma unroll
    for (int ij = 0; ij < 9; ++ij) {
        const int fe = ij * 16 + 2 * s8;     // even-frame weight; fe+1 = odd
        const int a = fe / 18;               // (fe+1)/18 == a (fe even)
        const float be = bconv[fe], bo = bconv[fe + 1];
        float2 we = make_float2(be, be);
        float2 wo = make_float2(bo, bo);
        #pragma unroll
        for (int b = 0; b < 9; ++b) {
            const float2 c2 = *(const float2*)(CR + (a * 9 + b) * 56 + qd * 2);
            const float wce = wconv[fe * 9 + b];
            const float wco = wconv[fe * 9 + 9 + b];
            we.x += c2.x * wce; we.y += c2.y * wce;
            wo.x += c2.x * wco; wo.y += c2.y * wco;
        }
        We[ij] = we; Wo[ij] = wo;
    }

    // ================= phase 3: barrier-free weighted gather =================
    float* ob = out + (size_t)n * 256 * HW + r0 * WID + qd * 2;

    #pragma unroll 2
    for (int k = 0; k < 32; ++k) {
        const int ch = k * 8 + s8;
        const float* pe = xe + (size_t)ch * HW;
        const float* po = xo + (size_t)ch * HW;

        float2 acc = make_float2(0.f, 0.f);
        #pragma unroll
        for (int di = 0; di < 3; ++di) {
            const float2 Ev = *(const float2*)(pe + rb[di]);
            const float2 Ov = *(const float2*)(po + rb[di]);
            float2 TEm, TEp, TOm, TOp;
            MKTAPS2(Ev, TEm, TEp)
            MKTAPS2(Ov, TOm, TOp)
            fma2(acc, TEm, We[di * 3 + 0]); fma2(acc, TOm, Wo[di * 3 + 0]);
            fma2(acc, Ev,  We[di * 3 + 1]); fma2(acc, Ov,  Wo[di * 3 + 1]);
            fma2(acc, TEp, We[di * 3 + 2]); fma2(acc, TOp, Wo[di * 3 + 2]);
        }
        if (act) *(float2*)(ob + (size_t)ch * HW) = acc;
    }
#undef MKTAPS2
}

// partial BN stats: block bid -> channel bid>>3, frame-pair slice bid&7 (4 pairs)
__global__ void tf_stats_part(const float* __restrict__ out,
                              float* __restrict__ ps, float* __restrict__ pq)
{
    const int ch = blockIdx.x >> 3;
    const int sl = blockIdx.x & 7;
    const int t = threadIdx.x;

    float s = 0.f, q = 0.f;
    #pragma unroll
    for (int k = 0; k < 4; ++k) {
        const float4* p = (const float4*)(out + ((size_t)(4 * sl + k) * 256 + ch) * HW);
        for (int i = t; i < 784; i += 256) {
            const float4 v = p[i];
            s += v.x + v.y + v.z + v.w;
            q += v.x * v.x + v.y * v.y + v.z * v.z + v.w * v.w;
        }
    }
    #pragma unroll
    for (int o = 32; o >= 1; o >>= 1) {
        s += __shfl_xor(s, o);
        q += __shfl_xor(q, o);
    }
    __shared__ float rs[4], rq[4];
    if ((t & 63) == 0) { rs[t >> 6] = s; rq[t >> 6] = q; }
    __syncthreads();
    if (t == 0) {
        ps[blockIdx.x] = rs[0] + rs[1] + rs[2] + rs[3];
        pq[blockIdx.x] = rq[0] + rq[1] + rq[2] + rq[3];
    }
}

__global__ void tf_stats_fin(const float* __restrict__ ps, const float* __restrict__ pq,
                             const float* __restrict__ gamma, const float* __restrict__ beta,
                             float* __restrict__ AB)
{
    const int ch = threadIdx.x;   // 256 threads, 1 block
    float s = 0.f, q = 0.f;
    #pragma unroll
    for (int sl = 0; sl < 8; ++sl) {
        s += ps[ch * 8 + sl];
        q += pq[ch * 8 + sl];
    }
    const float inv = 1.f / 100352.f;   // nt2*h*w
    const float mean = s * inv;
    const float var = q * inv - mean * mean;
    const float rstd = rsqrtf(var + 1e-5f);
    const float A = gamma[ch] * rstd;
    AB[ch] = A;
    AB[256 + ch] = beta[ch] - mean * A;
}

__global__ void tf_norm(float* __restrict__ out, const float* __restrict__ AB)
{
    const unsigned total4 = 32u * 256u * 784u;  // 6,422,528 float4
    unsigned i = blockIdx.x * 256u + threadIdx.x;
    const unsigned stride = gridDim.x * 256u;
    float4* o4 = (float4*)out;
    for (; i < total4; i += stride) {
        const unsigned ch = (i / 784u) & 255u;
        const float A = AB[ch], B = AB[256 + ch];
        float4 v = o4[i];
        v.x = v.x * A + B;
        v.y = v.y * A + B;
        v.z = v.z * A + B;
        v.w = v.w * A + B;
        o4[i] = v;
    }
}

extern "C" void kernel_launch(void* const* d_in, const int* in_sizes, int n_in,
                              void* d_out, int out_size, void* d_ws, size_t ws_size,
                              hipStream_t stream) {
    const float* x     = (const float*)d_in[0];
    const float* wconv = (const float*)d_in[1];
    const float* bconv = (const float*)d_in[2];
    const float* gamma = (const float*)d_in[3];
    const float* beta  = (const float*)d_in[4];
    float* out = (float*)d_out;

    float* ps = (float*)d_ws;        // [2048]
    float* pq = ps + 2048;           // [2048]
    float* AB = pq + 2048;           // [512]

    tf_fused<<<NBLK, 256, 0, stream>>>(x, wconv, bconv, out);
    tf_stats_part<<<2048, 256, 0, stream>>>(out, ps, pq);
    tf_stats_fin<<<1, 256, 0, stream>>>(ps, pq, gamma, beta, AB);
    tf_norm<<<2048, 256, 0, stream>>>(out, AB);
}